// Round 16
// baseline (113.795 us; speedup 1.0000x reference)
//
#include <hip/hip_runtime.h>
#include <stdint.h>

typedef unsigned short u16;
typedef unsigned int   u32;
typedef __attribute__((ext_vector_type(8)))  short bhalf8;   // 8 bf16 = 4 VGPRs
typedef __attribute__((ext_vector_type(16))) float f32x16;

#define B_ROWS 4096
#define I_DIM  1024
#define O_DIM  1024
#define N_D    6
#define K_LEG  (I_DIM * N_D)   /* 6144 */

#define BM 128
#define BN 128
#define BK 32
#define NS 56                   /* BK32 K-tiles per split (224 total / 4) */
#define SLOT 16384              /* A 8KB + B 8KB */
#define LDS_BYTES 49152         /* 3-slot ring -> 3 blocks/CU */

// float -> bf16 round-to-nearest-even
__device__ __forceinline__ u16 f2b(float f) {
  u32 u = __float_as_uint(f);
  return (u16)((u + 0x7fffu + ((u >> 16) & 1u)) >> 16);
}
__device__ __forceinline__ float b2f(u16 h) {
  return __uint_as_float((u32)h << 16);
}

// async global->LDS, 16B per lane; LDS dest = wave-uniform base + lane*16
__device__ __forceinline__ void gld_lds16(const void* g, void* l) {
  __builtin_amdgcn_global_load_lds(
      (const __attribute__((address_space(1))) u32*)(uintptr_t)g,
      (__attribute__((address_space(3))) u32*)(u32)(uintptr_t)l, 16, 0, 0);
}

// ---- prep (one launch):
//  blocks [0,1024):    Bb[o][i] = bf16(bw[i][o]) via 32x32 LDS tile
//  blocks [1024,2048): Bl[o][i*6+d] = bf16(lw[i][o][d]) via LDS microvector tile
//  blocks [2048,6144): per-row min/max + Legendre basis -> Ab, Al
#define RS 201
__global__ void k_prep(const float* __restrict__ bw, const float* __restrict__ lw,
                       const float* __restrict__ x,
                       u16* __restrict__ Bb, u16* __restrict__ Bl,
                       u16* __restrict__ Ab, u16* __restrict__ Al) {
  __shared__ float t[32 * RS];
  if (blockIdx.x < 1024) {
    const int bx = blockIdx.x & 31, by = blockIdx.x >> 5;
    const int i0 = by * 32, o0 = bx * 32;
    const int c = threadIdx.x & 31, r0 = threadIdx.x >> 5;
    #pragma unroll
    for (int k = 0; k < 4; ++k) {
      int r = r0 + k * 8;
      t[r * 33 + c] = bw[(size_t)(i0 + r) * O_DIM + o0 + c];
    }
    __syncthreads();
    #pragma unroll
    for (int k = 0; k < 4; ++k) {
      int r = r0 + k * 8;
      Bb[(size_t)(o0 + r) * I_DIM + i0 + c] = f2b(t[c * 33 + r]);
    }
  } else if (blockIdx.x < 2048) {
    const int blk = blockIdx.x - 1024;
    const int bx = blk & 31, by = blk >> 5;
    const int i0 = by * 32, o0 = bx * 32;
    for (int q = threadIdx.x; q < 32 * 48; q += 256) {
      int ri = q / 48, s4 = q % 48;
      float4 v = *(const float4*)(lw + (size_t)(i0 + ri) * (O_DIM * N_D) + o0 * N_D + s4 * 4);
      float* p = t + ri * RS + s4 * 4;
      p[0] = v.x; p[1] = v.y; p[2] = v.z; p[3] = v.w;
    }
    __syncthreads();
    for (int q = threadIdx.x; q < 32 * 96; q += 256) {
      int ro = q / 96, k = q % 96;
      int e0 = 2 * k, e1 = 2 * k + 1;
      float v0 = t[(e0 / 6) * RS + ro * 6 + (e0 % 6)];
      float v1 = t[(e1 / 6) * RS + ro * 6 + (e1 % 6)];
      u32* dst = (u32*)(Bl + (size_t)(o0 + ro) * K_LEG + i0 * N_D);
      dst[k] = (u32)f2b(v0) | ((u32)f2b(v1) << 16);
    }
  } else {
    const int b = blockIdx.x - 2048;
    const int tt = threadIdx.x;
    float4 v = ((const float4*)(x + (size_t)b * I_DIM))[tt];
    float mn = fminf(fminf(v.x, v.y), fminf(v.z, v.w));
    float mx = fmaxf(fmaxf(v.x, v.y), fmaxf(v.z, v.w));
    #pragma unroll
    for (int off = 32; off > 0; off >>= 1) {
      mn = fminf(mn, __shfl_xor(mn, off, 64));
      mx = fmaxf(mx, __shfl_xor(mx, off, 64));
    }
    __shared__ float smn[4], smx[4];
    if ((tt & 63) == 0) { smn[tt >> 6] = mn; smx[tt >> 6] = mx; }
    __syncthreads();
    mn = fminf(fminf(smn[0], smn[1]), fminf(smn[2], smn[3]));
    mx = fmaxf(fmaxf(smx[0], smx[1]), fmaxf(smx[2], smx[3]));
    float sc = 2.0f / (mx - mn + 1e-7f);

    float xs[4] = {v.x, v.y, v.z, v.w};
    u32 lb[12];
    #pragma unroll
    for (int e = 0; e < 4; ++e) {
      float xv = xs[e];
      float xn = (xv - mn) * sc - 1.0f;
      float p0 = 1.0f, p1 = xn;
      float p2 = (3.0f * xn * p1 - 1.0f * p0) * (1.0f / 2.0f);
      float p3 = (5.0f * xn * p2 - 2.0f * p1) * (1.0f / 3.0f);
      float p4 = (7.0f * xn * p3 - 3.0f * p2) * (1.0f / 4.0f);
      float p5 = (9.0f * xn * p4 - 4.0f * p3) * (1.0f / 5.0f);
      lb[e * 3 + 0] = (u32)f2b(xv * p0) | ((u32)f2b(xv * p1) << 16);
      lb[e * 3 + 1] = (u32)f2b(xv * p2) | ((u32)f2b(xv * p3) << 16);
      lb[e * 3 + 2] = (u32)f2b(xv * p4) | ((u32)f2b(xv * p5) << 16);
    }
    u32 a0 = (u32)f2b(xs[0]) | ((u32)f2b(xs[1]) << 16);
    u32 a1 = (u32)f2b(xs[2]) | ((u32)f2b(xs[3]) << 16);
    *(uint2*)(Ab + (size_t)b * I_DIM + tt * 4) = make_uint2(a0, a1);
    uint4* dl = (uint4*)(Al + (size_t)b * K_LEG + tt * 24);
    dl[0] = make_uint4(lb[0], lb[1], lb[2], lb[3]);
    dl[1] = make_uint4(lb[4], lb[5], lb[6], lb[7]);
    dl[2] = make_uint4(lb[8], lb[9], lb[10], lb[11]);
  }
}

// ---- fused split-K=4 GEMM, occupancy experiment: 128x128 tile, 4 waves,
//      32x32x16 MFMA, BK=32, 3-slot LDS ring (48KB) stage-ahead-1,
//      3 blocks/CU = 12 waves/CU (1.5x all prior configs), 1 barrier/tile,
//      counted vmcnt(4) (never 0 until last tile).
// bid = split*256 + by*32 + bx  -> XCD = bx%8 (L2-local staging streams, R15)
// split 0: base 32 tiles -> silu(acc) -> leg [0,24) -> f32 out
// splits 1..3: leg [24+56(s-1), 24+56s) -> bf16 partial
__global__ __launch_bounds__(256, 3) void k_gemm(
    const u16* __restrict__ Ab, const u16* __restrict__ Bb,
    const u16* __restrict__ Al, const u16* __restrict__ Bl,
    float* __restrict__ out, u16* __restrict__ Pb) {
  extern __shared__ char lds[];

  const int tid  = threadIdx.x;
  const int wave = tid >> 6;
  const int lane = tid & 63;
  const int wm = wave >> 1;            // 0..1: 64-row band
  const int wn = wave & 1;             // 0..1: 64-col band
  const u32 lr = (u32)lane & 31;       // 32x32 frag row/col
  const u32 hi = (u32)lane >> 5;       // k half: k = hi*8 + j

  const int bid   = blockIdx.x;        // 1024 blocks
  const int split = bid >> 8;          // 0..3
  const int rem   = bid & 255;
  const int by    = rem >> 5;          // 0..7
  const int bx    = rem & 31;          // 0..31  (XCD = bx%8)
  const size_t brow = (size_t)bx * BM;
  const size_t bcol = (size_t)by * BN;
  const bool s0 = (split == 0);
  const int legbase = s0 ? 0 : (24 + 56 * (split - 1));

  // staging: thread t -> row r4 = t>>2 (0..63), chunk-pos t&3;
  // source chunk pre-swizzled: key(r) = ((r>>1)&3)^((r>>3)&3) (involution)
  const int r4 = tid >> 2;
  const u32 skey = (((u32)r4 >> 1) & 3) ^ (((u32)r4 >> 3) & 3);
  const size_t cs = (size_t)(((u32)(tid & 3) ^ skey) * 8);

  const u16 *gA0, *gA1, *gB0, *gB1;
  auto set_ptrs = [&](const u16* A, const u16* Bt, size_t ldk, size_t kt) {
    const size_t ko = kt * BK + cs;
    gA0 = A  + (brow + r4) * ldk + ko;
    gA1 = A  + (brow + 64 + r4) * ldk + ko;
    gB0 = Bt + (bcol + r4) * ldk + ko;
    gB1 = Bt + (bcol + 64 + r4) * ldk + ko;
  };
  if (s0) set_ptrs(Ab, Bb, I_DIM, 0);
  else    set_ptrs(Al, Bl, K_LEG, (size_t)legbase);

  // stage K-tile v into slot base sb: A rows [0,64),[64,128) then B same
  auto stage = [&](int v, char* sb) {
    if (s0 && v == 32) set_ptrs(Al, Bl, K_LEG, 0);
    gld_lds16(gA0, sb + (size_t)tid * 16);
    gld_lds16(gA1, sb + 4096 + (size_t)tid * 16);
    gld_lds16(gB0, sb + 8192 + (size_t)tid * 16);
    gld_lds16(gB1, sb + 12288 + (size_t)tid * 16);
    gA0 += BK; gA1 += BK; gB0 += BK; gB1 += BK;
  };

  // frag reads: row r stores chunk c at pos c^key(r); key(row)==key(lr) for
  // all frag rows (offsets 32/64 don't touch key bits). chunk(kk) = kk*2+hi.
  const u32 key = ((lr >> 1) & 3) ^ ((lr >> 3) & 3);
  const u32 c00 = ((0 + hi) ^ key) * 16;   // kk = 0
  const u32 c10 = ((2 + hi) ^ key) * 16;   // kk = 1
  const u32 abase = ((u32)wm * 64 + lr) * 64;
  const u32 bbase = 8192u + ((u32)wn * 64 + lr) * 64;

  f32x16 acc[2][2] = {};
  bhalf8 a0[2], b0[2], a1[2], b1[2];   // kk0 / kk1 operand sets

  auto silu = [&]() {
    #pragma unroll
    for (int m = 0; m < 2; ++m)
      #pragma unroll
      for (int n = 0; n < 2; ++n)
        #pragma unroll
        for (int j = 0; j < 16; ++j) {
          float v = acc[m][n][j];
          acc[m][n][j] = v / (1.0f + __expf(-v));
        }
  };

#define RD(AA, BB, SB_, CH) do {                                              \
    BB[0] = *(const bhalf8*)((SB_) + bbase + (CH));                           \
    BB[1] = *(const bhalf8*)((SB_) + bbase + 2048 + (CH));                    \
    AA[0] = *(const bhalf8*)((SB_) + abase + (CH));                           \
    AA[1] = *(const bhalf8*)((SB_) + abase + 2048 + (CH));                    \
  } while (0)

#define MM(AA, BB) do {                                                       \
    __builtin_amdgcn_sched_barrier(0);                                        \
    __builtin_amdgcn_s_setprio(1);                                            \
    _Pragma("unroll")                                                         \
    for (int m = 0; m < 2; ++m)                                               \
      _Pragma("unroll")                                                       \
      for (int n = 0; n < 2; ++n)                                             \
        acc[m][n] = __builtin_amdgcn_mfma_f32_32x32x16_bf16(AA[m], BB[n], acc[m][n], 0, 0, 0); \
    __builtin_amdgcn_s_setprio(0);                                            \
    __builtin_amdgcn_sched_barrier(0);                                        \
  } while (0)

  // TILE(u): [stage u+1 into NXT]; vmcnt -> tile u landed; barrier; read both
  // kk-halves of CUR; MFMA. Slot ring: write u+1 vs reads u / laggard u-1 ->
  // distances 1,2 mod 3 != 0 -> race-free with the single barrier.
#define TILE(u, CUR, NXT, DOSTG, WTN) do {                                    \
    const int u_ = (u);                                                       \
    if (s0 && u_ == 32) silu();                                               \
    if (DOSTG) stage(u_ + 1, (NXT));                                          \
    asm volatile("s_waitcnt vmcnt(" #WTN ")" ::: "memory");                   \
    __builtin_amdgcn_s_barrier();                                             \
    RD(a0, b0, (CUR), c00);                                                   \
    RD(a1, b1, (CUR), c10);                                                   \
    MM(a0, b0);                                                               \
    MM(a1, b1);                                                               \
  } while (0)

  char* const s_0 = lds;
  char* const s_1 = lds + SLOT;
  char* const s_2 = lds + 2 * SLOT;

  // prologue: stage tile 0 into slot 0, certify
  stage(0, s_0);
  asm volatile("s_waitcnt vmcnt(0)" ::: "memory");
  __builtin_amdgcn_s_barrier();

  for (int t = 0; t < 18; ++t) {       // tiles 0..53
    const int u = t * 3;
    TILE(u,     s_0, s_1, true, 4);
    TILE(u + 1, s_1, s_2, true, 4);
    TILE(u + 2, s_2, s_0, true, 4);
  }
  TILE(54, s_0, s_1, true, 4);         // stages 55 -> slot 1
  TILE(55, s_1, s_2, false, 0);        // final tile: drain
#undef TILE
#undef MM
#undef RD

  // C/D layout (32x32, measured m74/m101): col = lane&31,
  // row = (reg&3) + 8*(reg>>2) + 4*(lane>>5)
  if (s0) {
    #pragma unroll
    for (int m = 0; m < 2; ++m)
      #pragma unroll
      for (int n = 0; n < 2; ++n) {
        const size_t rb = brow + wm * 64 + m * 32 + 4 * hi;
        const size_t c  = bcol + wn * 64 + n * 32 + lr;
        #pragma unroll
        for (int j = 0; j < 16; ++j) {
          const size_t r = rb + (j & 3) + 8 * (j >> 2);
          out[r * O_DIM + c] = acc[m][n][j];
        }
      }
  } else {
    u16* dst = Pb + (size_t)(split - 1) * ((size_t)B_ROWS * O_DIM);
    #pragma unroll
    for (int m = 0; m < 2; ++m)
      #pragma unroll
      for (int n = 0; n < 2; ++n) {
        const size_t rb = brow + wm * 64 + m * 32 + 4 * hi;
        const size_t c  = bcol + wn * 64 + n * 32 + lr;
        #pragma unroll
        for (int j = 0; j < 16; ++j) {
          const size_t r = rb + (j & 3) + 8 * (j >> 2);
          dst[r * O_DIM + c] = f2b(acc[m][n][j]);
        }
      }
  }
}

// ---- final: out += Pb0 + Pb1 + Pb2 (bf16 partials) ----
__global__ void k_reduce(float* __restrict__ out, const u16* __restrict__ Pb) {
  const size_t i = (size_t)blockIdx.x * 256 + threadIdx.x;   // per float4
  const size_t NE = (size_t)B_ROWS * O_DIM;
  float4 a = ((const float4*)out)[i];
  ushort4 p0 = ((const ushort4*)Pb)[i];
  ushort4 p1 = ((const ushort4*)(Pb + NE))[i];
  ushort4 p2 = ((const ushort4*)(Pb + 2 * NE))[i];
  a.x += b2f(p0.x) + b2f(p1.x) + b2f(p2.x);
  a.y += b2f(p0.y) + b2f(p1.y) + b2f(p2.y);
  a.z += b2f(p0.z) + b2f(p1.z) + b2f(p2.z);
  a.w += b2f(p0.w) + b2f(p1.w) + b2f(p2.w);
  ((float4*)out)[i] = a;
}

extern "C" void kernel_launch(void* const* d_in, const int* in_sizes, int n_in,
                              void* d_out, int out_size, void* d_ws, size_t ws_size,
                              hipStream_t stream) {
  const float* x  = (const float*)d_in[0];   // [4096][1024]
  const float* bw = (const float*)d_in[1];   // [1024][1024]
  const float* lw = (const float*)d_in[2];   // [1024][1024][6]
  float* out = (float*)d_out;                // [4096][1024]

  char* w = (char*)d_ws;
  u16* Ab = (u16*)(w);                                  //  8 MiB [4096][1024]
  u16* Al = (u16*)(w + (size_t)8   * 1024 * 1024);      // 48 MiB [4096][6144]
  u16* Bb = (u16*)(w + (size_t)56  * 1024 * 1024);      //  2 MiB [1024][1024]
  u16* Bl = (u16*)(w + (size_t)58  * 1024 * 1024);      // 12 MiB [1024][6144]
  u16* Pb = (u16*)(w + (size_t)72  * 1024 * 1024);      // 24 MiB: 3 x [4096][1024] bf16

  hipFuncSetAttribute((const void*)k_gemm,
                      hipFuncAttributeMaxDynamicSharedMemorySize, LDS_BYTES);

  k_prep  <<<dim3(2048 + B_ROWS), 256, 0, stream>>>(bw, lw, x, Bb, Bl, Ab, Al);
  k_gemm  <<<dim3(4 * (B_ROWS / BM) * (O_DIM / BN)), 256, LDS_BYTES, stream>>>(Ab, Bb, Al, Bl, out, Pb);
  k_reduce<<<dim3((B_ROWS * O_DIM / 4) / 256), 256, 0, stream>>>(out, Pb);
}

// Round 17
// 101.143 us; speedup vs baseline: 1.1251x; 1.1251x over previous
//
#include <hip/hip_runtime.h>
#include <stdint.h>

typedef unsigned short u16;
typedef unsigned int   u32;
typedef __attribute__((ext_vector_type(8)))  short bhalf8;   // 8 bf16 = 4 VGPRs
typedef __attribute__((ext_vector_type(16))) float f32x16;

#define B_ROWS 4096
#define I_DIM  1024
#define O_DIM  1024
#define N_D    6
#define K_LEG  (I_DIM * N_D)   /* 6144 */

#define BM 256
#define BN 256
#define BK 32
#define NU 56                   /* K-tiles per split (224 total / 4 splits) */
#define SLOT_BYTES 32768        /* A 16KB + B 16KB */
#define LDS_BYTES  131072       /* 4-slot ring */

// float -> bf16 round-to-nearest-even
__device__ __forceinline__ u16 f2b(float f) {
  u32 u = __float_as_uint(f);
  return (u16)((u + 0x7fffu + ((u >> 16) & 1u)) >> 16);
}
__device__ __forceinline__ float b2f(u16 h) {
  return __uint_as_float((u32)h << 16);
}

// async global->LDS, 16B per lane; LDS dest = wave-uniform base + lane*16
__device__ __forceinline__ void gld_lds16(const void* g, void* l) {
  __builtin_amdgcn_global_load_lds(
      (const __attribute__((address_space(1))) u32*)(uintptr_t)g,
      (__attribute__((address_space(3))) u32*)(u32)(uintptr_t)l, 16, 0, 0);
}

// ---- prep (one launch):
//  blocks [0,1024):    Bb[o][i] = bf16(bw[i][o]) via 32x32 LDS tile
//  blocks [1024,2048): Bl[o][i*6+d] = bf16(lw[i][o][d]) via LDS microvector tile
//  blocks [2048,6144): per-row min/max + Legendre basis -> Ab, Al
#define RS 201
__global__ void k_prep(const float* __restrict__ bw, const float* __restrict__ lw,
                       const float* __restrict__ x,
                       u16* __restrict__ Bb, u16* __restrict__ Bl,
                       u16* __restrict__ Ab, u16* __restrict__ Al) {
  __shared__ float t[32 * RS];
  if (blockIdx.x < 1024) {
    const int bx = blockIdx.x & 31, by = blockIdx.x >> 5;
    const int i0 = by * 32, o0 = bx * 32;
    const int c = threadIdx.x & 31, r0 = threadIdx.x >> 5;
    #pragma unroll
    for (int k = 0; k < 4; ++k) {
      int r = r0 + k * 8;
      t[r * 33 + c] = bw[(size_t)(i0 + r) * O_DIM + o0 + c];
    }
    __syncthreads();
    #pragma unroll
    for (int k = 0; k < 4; ++k) {
      int r = r0 + k * 8;
      Bb[(size_t)(o0 + r) * I_DIM + i0 + c] = f2b(t[c * 33 + r]);
    }
  } else if (blockIdx.x < 2048) {
    const int blk = blockIdx.x - 1024;
    const int bx = blk & 31, by = blk >> 5;
    const int i0 = by * 32, o0 = bx * 32;
    for (int q = threadIdx.x; q < 32 * 48; q += 256) {
      int ri = q / 48, s4 = q % 48;
      float4 v = *(const float4*)(lw + (size_t)(i0 + ri) * (O_DIM * N_D) + o0 * N_D + s4 * 4);
      float* p = t + ri * RS + s4 * 4;
      p[0] = v.x; p[1] = v.y; p[2] = v.z; p[3] = v.w;
    }
    __syncthreads();
    for (int q = threadIdx.x; q < 32 * 96; q += 256) {
      int ro = q / 96, k = q % 96;
      int e0 = 2 * k, e1 = 2 * k + 1;
      float v0 = t[(e0 / 6) * RS + ro * 6 + (e0 % 6)];
      float v1 = t[(e1 / 6) * RS + ro * 6 + (e1 % 6)];
      u32* dst = (u32*)(Bl + (size_t)(o0 + ro) * K_LEG + i0 * N_D);
      dst[k] = (u32)f2b(v0) | ((u32)f2b(v1) << 16);
    }
  } else {
    const int b = blockIdx.x - 2048;
    const int tt = threadIdx.x;
    float4 v = ((const float4*)(x + (size_t)b * I_DIM))[tt];
    float mn = fminf(fminf(v.x, v.y), fminf(v.z, v.w));
    float mx = fmaxf(fmaxf(v.x, v.y), fmaxf(v.z, v.w));
    #pragma unroll
    for (int off = 32; off > 0; off >>= 1) {
      mn = fminf(mn, __shfl_xor(mn, off, 64));
      mx = fmaxf(mx, __shfl_xor(mx, off, 64));
    }
    __shared__ float smn[4], smx[4];
    if ((tt & 63) == 0) { smn[tt >> 6] = mn; smx[tt >> 6] = mx; }
    __syncthreads();
    mn = fminf(fminf(smn[0], smn[1]), fminf(smn[2], smn[3]));
    mx = fmaxf(fmaxf(smx[0], smx[1]), fmaxf(smx[2], smx[3]));
    float sc = 2.0f / (mx - mn + 1e-7f);

    float xs[4] = {v.x, v.y, v.z, v.w};
    u32 lb[12];
    #pragma unroll
    for (int e = 0; e < 4; ++e) {
      float xv = xs[e];
      float xn = (xv - mn) * sc - 1.0f;
      float p0 = 1.0f, p1 = xn;
      float p2 = (3.0f * xn * p1 - 1.0f * p0) * (1.0f / 2.0f);
      float p3 = (5.0f * xn * p2 - 2.0f * p1) * (1.0f / 3.0f);
      float p4 = (7.0f * xn * p3 - 3.0f * p2) * (1.0f / 4.0f);
      float p5 = (9.0f * xn * p4 - 4.0f * p3) * (1.0f / 5.0f);
      lb[e * 3 + 0] = (u32)f2b(xv * p0) | ((u32)f2b(xv * p1) << 16);
      lb[e * 3 + 1] = (u32)f2b(xv * p2) | ((u32)f2b(xv * p3) << 16);
      lb[e * 3 + 2] = (u32)f2b(xv * p4) | ((u32)f2b(xv * p5) << 16);
    }
    u32 a0 = (u32)f2b(xs[0]) | ((u32)f2b(xs[1]) << 16);
    u32 a1 = (u32)f2b(xs[2]) | ((u32)f2b(xs[3]) << 16);
    *(uint2*)(Ab + (size_t)b * I_DIM + tt * 4) = make_uint2(a0, a1);
    uint4* dl = (uint4*)(Al + (size_t)b * K_LEG + tt * 24);
    dl[0] = make_uint4(lb[0], lb[1], lb[2], lb[3]);
    dl[1] = make_uint4(lb[4], lb[5], lb[6], lb[7]);
    dl[2] = make_uint4(lb[8], lb[9], lb[10], lb[11]);
  }
}

// ---- fused split-K=4 GEMM (R9/R15 structure — 14-variant family best):
//      256x256, 8 waves, 32x32x16 MFMA, 4-slot LDS ring, 3-set rotating reg
//      pipeline (frags prefetched one FULL tile ahead, compiler-counted lgkm),
//      counted vmcnt(4), 1 barrier/tile, XCD-local bid decode.
// ALL splits store bf16 partials to Pb[split] (k_reduce sums 4 planes).
__global__ __launch_bounds__(512, 2) void k_gemm(
    const u16* __restrict__ Ab, const u16* __restrict__ Bb,
    const u16* __restrict__ Al, const u16* __restrict__ Bl,
    u16* __restrict__ Pb) {
  extern __shared__ char lds[];

  const int tid  = threadIdx.x;
  const int wave = tid >> 6;
  const int lane = tid & 63;
  const int wm = wave >> 2;            // 0..1: 128-row band
  const int wn = wave & 3;             // 0..3: 64-col band
  const u32 lr = (u32)lane & 31;       // 32x32 frag row/col
  const u32 hi = (u32)lane >> 5;       // k half: k = hi*8 + j

  // XCD-locality decode: p = bx*4+split in low 6 bits -> XCD = p%8
  const int bid   = blockIdx.x;        // 256 blocks = 1/CU
  const int by    = bid >> 6;          // 0..3
  const int p_    = bid & 63;
  const int bx    = p_ >> 2;           // 0..15
  const int split = p_ & 3;
  const size_t brow = (size_t)bx * BM;
  const size_t bcol = (size_t)by * BN;
  const bool s0 = (split == 0);
  const int legbase = s0 ? 0 : (24 + 56 * (split - 1));

  // staging: thread t covers (row = r4, chunk-pos = t&3) of each 128-row half;
  // source chunk pre-swizzled: g = pos ^ key(row), key(r) = ((r>>1)&3)^((r>>3)&3)
  const int r4 = tid >> 2;
  const u32 skey = (((u32)r4 >> 1) & 3) ^ (((u32)r4 >> 3) & 3);
  const size_t cs = (size_t)(((u32)(tid & 3) ^ skey) * 8);
  char* const l0 = lds + (u32)wave * 1024;

  const u16 *gA0, *gA1, *gB0, *gB1;
  auto set_ptrs = [&](const u16* A, const u16* Bt, size_t ldk, size_t kt) {
    const size_t ko = kt * BK + cs;
    gA0 = A  + (brow + r4) * ldk + ko;
    gA1 = A  + (brow + 128 + r4) * ldk + ko;
    gB0 = Bt + (bcol + r4) * ldk + ko;
    gB1 = Bt + (bcol + 128 + r4) * ldk + ko;
  };
  if (s0) set_ptrs(Ab, Bb, I_DIM, 0);
  else    set_ptrs(Al, Bl, K_LEG, (size_t)legbase);

  auto stage = [&](int v) {
    if (s0 && v == 32) set_ptrs(Al, Bl, K_LEG, 0);
    char* d = l0 + (size_t)(v & 3) * SLOT_BYTES;
    gld_lds16(gA0, d);          gld_lds16(gA1, d + 8192);
    gld_lds16(gB0, d + 16384);  gld_lds16(gB1, d + 24576);
    gA0 += BK; gA1 += BK; gB0 += BK; gB1 += BK;
  };

  // frag-read offsets: chunk (kk*2+hi) stored at (kk*2+hi)^key(row)
  const u32 key = ((lr >> 1) & 3) ^ ((lr >> 3) & 3);
  const u32 c00 = ((0 + hi) ^ key) * 16;   // kk = 0
  const u32 c10 = ((2 + hi) ^ key) * 16;   // kk = 1
  const u32 abase_r = (u32)wm * 8192 + lr * 64;
  const u32 bbase_r = 16384u + ((u32)wn >> 1) * 8192 + ((u32)wn & 1) * 4096 + lr * 64;

  f32x16 acc[4][2] = {};
  bhalf8 a0[4], b0[2], a1[4], b1[2], a2[4], b2[2];   // 3 rotating operand sets

  auto silu = [&]() {
    #pragma unroll
    for (int m = 0; m < 4; ++m)
      #pragma unroll
      for (int n = 0; n < 2; ++n)
        #pragma unroll
        for (int j = 0; j < 16; ++j) {
          float v = acc[m][n][j];
          acc[m][n][j] = v / (1.0f + __expf(-v));
        }
  };

#define FILL(u1, CH, AA, BB) do {                                             \
    const char* pn_ = lds + (size_t)((u1) & 3) * SLOT_BYTES;                  \
    BB[0] = *(const bhalf8*)(pn_ + bbase_r + (CH));                           \
    BB[1] = *(const bhalf8*)(pn_ + bbase_r + 2048 + (CH));                    \
    AA[0] = *(const bhalf8*)(pn_ + abase_r + (CH));                           \
    AA[1] = *(const bhalf8*)(pn_ + abase_r + 2048 + (CH));                    \
    AA[2] = *(const bhalf8*)(pn_ + abase_r + 4096 + (CH));                    \
    AA[3] = *(const bhalf8*)(pn_ + abase_r + 6144 + (CH));                    \
  } while (0)

#define MM(AA, BB) do {                                                       \
    __builtin_amdgcn_sched_barrier(0);                                        \
    __builtin_amdgcn_s_setprio(1);                                            \
    _Pragma("unroll")                                                         \
    for (int m = 0; m < 4; ++m)                                               \
      _Pragma("unroll")                                                       \
      for (int n = 0; n < 2; ++n)                                             \
        acc[m][n] = __builtin_amdgcn_mfma_f32_32x32x16_bf16(AA[m], BB[n], acc[m][n], 0, 0, 0); \
    __builtin_amdgcn_s_setprio(0);                                            \
    __builtin_amdgcn_sched_barrier(0);                                        \
  } while (0)

  // TILE(u): consume sets P (kk0) and Q (kk1); fill R <- kk0(u+1), P <- kk1(u+1)
#define TILE(u, PA, PB, QA, QB, RA, RB) do {                                  \
    const int u_ = (u);                                                       \
    if (s0 && u_ == 32) silu();                                               \
    if (u_ <= NU - 3) {                                                       \
      stage(u_ + 2);                                                          \
      asm volatile("s_waitcnt vmcnt(4)" ::: "memory");  /* tile u+1 landed */ \
    } else {                                                                  \
      asm volatile("s_waitcnt vmcnt(0)" ::: "memory");                        \
    }                                                                         \
    __builtin_amdgcn_s_barrier();                                             \
    if (u_ < NU - 1) FILL(u_ + 1, c00, RA, RB);                               \
    MM(PA, PB);                                                               \
    if (u_ < NU - 1) FILL(u_ + 1, c10, PA, PB);                               \
    MM(QA, QB);                                                               \
  } while (0)

  // prologue: stage tiles 0,1; confirm tile 0; fill both halves of tile 0
  stage(0); stage(1);
  asm volatile("s_waitcnt vmcnt(4)" ::: "memory");
  __builtin_amdgcn_s_barrier();
  FILL(0, c00, a0, b0);
  FILL(0, c10, a1, b1);

  for (int t = 0; t < 18; ++t) {       // tiles 0..53
    const int u = t * 3;
    TILE(u,     a0, b0, a1, b1, a2, b2);
    TILE(u + 1, a2, b2, a0, b0, a1, b1);
    TILE(u + 2, a1, b1, a2, b2, a0, b0);
  }
  TILE(54, a0, b0, a1, b1, a2, b2);
  TILE(55, a2, b2, a0, b0, a1, b1);
#undef TILE
#undef MM
#undef FILL

  // C/D layout (32x32, measured m74/m101): col = lane&31,
  // row = (reg&3) + 8*(reg>>2) + 4*(lane>>5). bf16 partial for ALL splits.
  u16* dst = Pb + (size_t)split * ((size_t)B_ROWS * O_DIM);
  #pragma unroll
  for (int m = 0; m < 4; ++m)
    #pragma unroll
    for (int n = 0; n < 2; ++n) {
      const size_t rb = brow + wm * 128 + m * 32 + 4 * hi;
      const size_t c  = bcol + wn * 64 + n * 32 + lr;
      #pragma unroll
      for (int j = 0; j < 16; ++j) {
        const size_t r = rb + (j & 3) + 8 * (j >> 2);
        dst[r * O_DIM + c] = f2b(acc[m][n][j]);
      }
    }
}

// ---- final: out = Pb0 + Pb1 + Pb2 + Pb3 (bf16 partials, f32 sum) ----
__global__ void k_reduce(float* __restrict__ out, const u16* __restrict__ Pb) {
  const size_t i = (size_t)blockIdx.x * 256 + threadIdx.x;   // per float4
  const size_t NE = (size_t)B_ROWS * O_DIM;
  ushort4 p0 = ((const ushort4*)Pb)[i];
  ushort4 p1 = ((const ushort4*)(Pb + NE))[i];
  ushort4 p2 = ((const ushort4*)(Pb + 2 * NE))[i];
  ushort4 p3 = ((const ushort4*)(Pb + 3 * NE))[i];
  float4 a;
  a.x = b2f(p0.x) + b2f(p1.x) + b2f(p2.x) + b2f(p3.x);
  a.y = b2f(p0.y) + b2f(p1.y) + b2f(p2.y) + b2f(p3.y);
  a.z = b2f(p0.z) + b2f(p1.z) + b2f(p2.z) + b2f(p3.z);
  a.w = b2f(p0.w) + b2f(p1.w) + b2f(p2.w) + b2f(p3.w);
  ((float4*)out)[i] = a;
}

extern "C" void kernel_launch(void* const* d_in, const int* in_sizes, int n_in,
                              void* d_out, int out_size, void* d_ws, size_t ws_size,
                              hipStream_t stream) {
  const float* x  = (const float*)d_in[0];   // [4096][1024]
  const float* bw = (const float*)d_in[1];   // [1024][1024]
  const float* lw = (const float*)d_in[2];   // [1024][1024][6]
  float* out = (float*)d_out;                // [4096][1024]

  char* w = (char*)d_ws;
  u16* Ab = (u16*)(w);                                  //  8 MiB [4096][1024]
  u16* Al = (u16*)(w + (size_t)8   * 1024 * 1024);      // 48 MiB [4096][6144]
  u16* Bb = (u16*)(w + (size_t)56  * 1024 * 1024);      //  2 MiB [1024][1024]
  u16* Bl = (u16*)(w + (size_t)58  * 1024 * 1024);      // 12 MiB [1024][6144]
  u16* Pb = (u16*)(w + (size_t)72  * 1024 * 1024);      // 32 MiB: 4 x [4096][1024] bf16

  hipFuncSetAttribute((const void*)k_gemm,
                      hipFuncAttributeMaxDynamicSharedMemorySize, LDS_BYTES);

  k_prep  <<<dim3(2048 + B_ROWS), 256, 0, stream>>>(bw, lw, x, Bb, Bl, Ab, Al);
  k_gemm  <<<dim3(256), 512, LDS_BYTES, stream>>>(Ab, Bb, Al, Bl, Pb);
  k_reduce<<<dim3((B_ROWS * O_DIM / 4) / 256), 256, 0, stream>>>(out, Pb);
}